// Round 2
// baseline (952.416 us; speedup 1.0000x reference)
//
#include <hip/hip_runtime.h>
#include <stdint.h>
#include <stddef.h>

typedef __attribute__((ext_vector_type(8))) short bf16x8;
typedef __attribute__((ext_vector_type(4))) float f32x4;
typedef __attribute__((ext_vector_type(4))) unsigned short u16x4;

#define BATCH 2
#define SEQ 4096
#define NHEADS 16
#define DHEAD 64
#define DIM 1024
#define MTOT 8192
#define N1 3072

__device__ __forceinline__ unsigned short f2bf(float f) {
  union { float f; unsigned u; } x; x.f = f;
  unsigned r = x.u + 0x7fffu + ((x.u >> 16) & 1u);
  return (unsigned short)(r >> 16);
}

__device__ __forceinline__ void gload_lds16(const void* g, void* l) {
  __builtin_amdgcn_global_load_lds(
      (const __attribute__((address_space(1))) void*)g,
      (__attribute__((address_space(3))) void*)l, 16, 0, 0);
}

// ---------------- f32 -> bf16 elementwise ----------------
__global__ __launch_bounds__(256) void cvt_f2b(const float* __restrict__ in,
                                               unsigned short* __restrict__ out,
                                               int n4) {
  int i = blockIdx.x * 256 + threadIdx.x;
  if (i < n4) {
    f32x4 v = ((const f32x4*)in)[i];
    u16x4 o;
#pragma unroll
    for (int j = 0; j < 4; j++) o[j] = f2bf(v[j]);
    ((u16x4*)out)[i] = o;
  }
}

// ---------------- transpose+convert: f32 (R x C) -> bf16 (C x R) ----------
__global__ void transpose_cvt(const float* __restrict__ in,
                              unsigned short* __restrict__ out, int R, int C) {
  __shared__ unsigned short t[32][33];
  int tx = threadIdx.x, ty = threadIdx.y;
  int c0 = blockIdx.x * 32, r0 = blockIdx.y * 32;
#pragma unroll
  for (int i = 0; i < 4; i++)
    t[ty + i * 8][tx] = f2bf(in[(size_t)(r0 + ty + i * 8) * C + c0 + tx]);
  __syncthreads();
#pragma unroll
  for (int i = 0; i < 4; i++)
    out[(size_t)(c0 + ty + i * 8) * R + r0 + tx] = t[tx][ty + i * 8];
}

// ---------------- GEMM: C[M,N] = A[M,K] * Bt[N,K]^T, bf16 in ----
// MODE 0: scatter epilogue into Q (scaled 0.125), K, V-transposed bf16 buffers.
// MODE 1: plain row-major f32 store to Of with stride N.
template <int MODE>
__global__ __launch_bounds__(256) void gemm_bt(
    const unsigned short* __restrict__ A,
    const unsigned short* __restrict__ Bt,
    unsigned short* __restrict__ O0,
    unsigned short* __restrict__ O1,
    unsigned short* __restrict__ O2,
    float* __restrict__ Of,
    int N, int K) {
  __shared__ unsigned short Asl[128][32];
  __shared__ unsigned short Bsl[128][32];
  const int tid = threadIdx.x;
  const int lane = tid & 63, wv = tid >> 6;
  const int wr = wv >> 1, wc = wv & 1;
  const int m0 = blockIdx.x * 128, n0 = blockIdx.y * 128;
  const int lrow = lane >> 2, lcol = (lane & 3) * 8;
  const int fr = lane & 15, kc8 = (lane >> 4) * 8;
  f32x4 acc[4][4] = {};
  for (int k0 = 0; k0 < K; k0 += 32) {
#pragma unroll
    for (int c = 0; c < 2; c++) {
      int r = wv * 32 + c * 16 + lrow;
      gload_lds16(&A[(size_t)(m0 + r) * K + k0 + lcol], &Asl[wv * 32 + c * 16][0]);
      gload_lds16(&Bt[(size_t)(n0 + r) * K + k0 + lcol], &Bsl[wv * 32 + c * 16][0]);
    }
    __syncthreads();
    bf16x8 af[4], bfr[4];
#pragma unroll
    for (int i = 0; i < 4; i++)
      af[i] = *(const bf16x8*)&Asl[wr * 64 + i * 16 + fr][kc8];
#pragma unroll
    for (int j = 0; j < 4; j++)
      bfr[j] = *(const bf16x8*)&Bsl[wc * 64 + j * 16 + fr][kc8];
#pragma unroll
    for (int i = 0; i < 4; i++)
#pragma unroll
      for (int j = 0; j < 4; j++)
        acc[i][j] = __builtin_amdgcn_mfma_f32_16x16x32_bf16(af[i], bfr[j], acc[i][j], 0, 0, 0);
    __syncthreads();
  }
  const int rq = (lane >> 4) * 4;
#pragma unroll
  for (int i = 0; i < 4; i++) {
#pragma unroll
    for (int j = 0; j < 4; j++) {
#pragma unroll
      for (int r = 0; r < 4; r++) {
        int row = m0 + wr * 64 + i * 16 + rq + r;
        int col = n0 + wc * 64 + j * 16 + fr;
        float v = acc[i][j][r];
        if (MODE == 0) {
          int w = col >> 10, rem = col & 1023;
          int h = rem >> 6, d = rem & 63;
          int b = row >> 12, n = row & 4095;
          size_t bh = (size_t)b * NHEADS + h;
          if (w == 0)      O0[(bh * SEQ + n) * DHEAD + d] = f2bf(v * 0.125f);
          else if (w == 1) O1[(bh * SEQ + n) * DHEAD + d] = f2bf(v);
          else             O2[(bh * DHEAD + d) * SEQ + n] = f2bf(v);
        } else {
          Of[(size_t)row * N + col] = v;
        }
      }
    }
  }
}

// ---------------- causal flash attention ----------------
// Q: [BH][SEQ][64] (pre-scaled), K: [BH][SEQ][64], Vt: [BH][64][SEQ]
// AO: [BATCH*SEQ][DIM] row-major bf16
__global__ __launch_bounds__(256) void attn_causal(
    const unsigned short* __restrict__ Q,
    const unsigned short* __restrict__ Kb,
    const unsigned short* __restrict__ Vt,
    unsigned short* __restrict__ AO) {
  const int bh = blockIdx.y;   // b*16 + h
  const int qt = blockIdx.x;   // q tile of 64 rows
  const int tid = threadIdx.x, lane = tid & 63, wv = tid >> 6;
  const int q0 = qt * 64;
  const unsigned short* Qp = Q + (size_t)bh * SEQ * DHEAD;
  const unsigned short* Kp = Kb + (size_t)bh * SEQ * DHEAD;
  const unsigned short* Vp = Vt + (size_t)bh * DHEAD * SEQ;
  const int fr = lane & 15, kc8 = (lane >> 4) * 8;
  const int rq = (lane >> 4) * 4;

  bf16x8 qf[2];
#pragma unroll
  for (int c = 0; c < 2; c++)
    qf[c] = *(const bf16x8*)&Qp[(size_t)(q0 + wv * 16 + fr) * DHEAD + c * 32 + kc8];

  f32x4 oacc[4] = {};           // 4 d-blocks of 16
  float mrow[4], lrow[4];
#pragma unroll
  for (int r = 0; r < 4; r++) { mrow[r] = -1e30f; lrow[r] = 0.f; }

  __shared__ unsigned short Pl[4][16][64];

  for (int kt = 0; kt <= qt; kt++) {
    const int k0 = kt * 64;
    // ---- S = Q K^T (pre-scaled Q) ----
    f32x4 s[4];
#pragma unroll
    for (int cb = 0; cb < 4; cb++) {
      bf16x8 kf0 = *(const bf16x8*)&Kp[(size_t)(k0 + cb * 16 + fr) * DHEAD + kc8];
      bf16x8 kf1 = *(const bf16x8*)&Kp[(size_t)(k0 + cb * 16 + fr) * DHEAD + 32 + kc8];
      f32x4 z = {};
      z = __builtin_amdgcn_mfma_f32_16x16x32_bf16(qf[0], kf0, z, 0, 0, 0);
      s[cb] = __builtin_amdgcn_mfma_f32_16x16x32_bf16(qf[1], kf1, z, 0, 0, 0);
    }
    // ---- causal mask on diagonal block ----
    if (kt == qt) {
#pragma unroll
      for (int cb = 0; cb < 4; cb++) {
        int kj = cb * 16 + fr;
#pragma unroll
        for (int r = 0; r < 4; r++) {
          int qi = wv * 16 + rq + r;
          if (kj > qi) s[cb][r] = -1e30f;
        }
      }
    }
    // ---- online softmax ----
    f32x4 p[4];
#pragma unroll
    for (int r = 0; r < 4; r++) {
      float t = fmaxf(fmaxf(s[0][r], s[1][r]), fmaxf(s[2][r], s[3][r]));
#pragma unroll
      for (int off = 1; off < 16; off <<= 1) t = fmaxf(t, __shfl_xor(t, off, 64));
      float mnew = fmaxf(mrow[r], t);
      float alpha = __expf(mrow[r] - mnew);
#pragma unroll
      for (int db = 0; db < 4; db++) oacc[db][r] *= alpha;
      float sum = 0.f;
#pragma unroll
      for (int cb = 0; cb < 4; cb++) {
        float pv = __expf(s[cb][r] - mnew);
        p[cb][r] = pv;
        sum += pv;
      }
#pragma unroll
      for (int off = 1; off < 16; off <<= 1) sum += __shfl_xor(sum, off, 64);
      lrow[r] = lrow[r] * alpha + sum;
      mrow[r] = mnew;
    }
    // ---- P -> LDS (bf16), per-wave region ----
#pragma unroll
    for (int cb = 0; cb < 4; cb++)
#pragma unroll
      for (int r = 0; r < 4; r++)
        Pl[wv][rq + r][cb * 16 + fr] = f2bf(p[cb][r]);
    __syncthreads();
    // ---- O += P V ----
    bf16x8 pa0 = *(const bf16x8*)&Pl[wv][fr][kc8];
    bf16x8 pa1 = *(const bf16x8*)&Pl[wv][fr][32 + kc8];
#pragma unroll
    for (int db = 0; db < 4; db++) {
      bf16x8 vf0 = *(const bf16x8*)&Vp[(size_t)(db * 16 + fr) * SEQ + k0 + kc8];
      bf16x8 vf1 = *(const bf16x8*)&Vp[(size_t)(db * 16 + fr) * SEQ + k0 + 32 + kc8];
      oacc[db] = __builtin_amdgcn_mfma_f32_16x16x32_bf16(pa0, vf0, oacc[db], 0, 0, 0);
      oacc[db] = __builtin_amdgcn_mfma_f32_16x16x32_bf16(pa1, vf1, oacc[db], 0, 0, 0);
    }
    __syncthreads();
  }

  // ---- finalize: O / l, write AO[b*SEQ+n][h*64+d] ----
  const int b = bh >> 4, h = bh & 15;
#pragma unroll
  for (int db = 0; db < 4; db++)
#pragma unroll
    for (int r = 0; r < 4; r++) {
      int n = q0 + wv * 16 + rq + r;
      int d = db * 16 + fr;
      float v = oacc[db][r] / lrow[r];
      AO[(size_t)(b * SEQ + n) * DIM + h * DHEAD + d] = f2bf(v);
    }
}

extern "C" void kernel_launch(void* const* d_in, const int* in_sizes, int n_in,
                              void* d_out, int out_size, void* d_ws, size_t ws_size,
                              hipStream_t stream) {
  const float* x    = (const float*)d_in[0]; // [8192][1024] f32
  const float* wqkv = (const float*)d_in[1]; // [1024][3072] f32
  const float* wout = (const float*)d_in[2]; // [1024][1024] f32
  float* out = (float*)d_out;                // [8192][1024] f32

  unsigned short* ws = (unsigned short*)d_ws;
  // xb and ao alias (xb dead after gemm1; ao written in attn)
  unsigned short* xb = ws;                                   // [8192][1024]
  unsigned short* ao = ws;                                   // [8192][1024]
  unsigned short* wqkv_t = ws + (size_t)MTOT * DIM;          // [3072][1024]
  unsigned short* wout_t = wqkv_t + (size_t)N1 * DIM;        // [1024][1024]
  unsigned short* qb = wout_t + (size_t)DIM * DIM;           // [32][4096][64]
  unsigned short* kb = qb + (size_t)BATCH * NHEADS * SEQ * DHEAD;
  unsigned short* vt = kb + (size_t)BATCH * NHEADS * SEQ * DHEAD; // [32][64][4096]

  // x -> bf16
  int n4 = (MTOT * DIM) / 4;
  hipLaunchKernelGGL(cvt_f2b, dim3(n4 / 256), dim3(256), 0, stream, x, xb, n4);

  dim3 tb(32, 8);
  hipLaunchKernelGGL(transpose_cvt, dim3(N1 / 32, DIM / 32), tb, 0, stream,
                     wqkv, wqkv_t, DIM, N1);
  hipLaunchKernelGGL(transpose_cvt, dim3(DIM / 32, DIM / 32), tb, 0, stream,
                     wout, wout_t, DIM, DIM);

  hipLaunchKernelGGL((gemm_bt<0>), dim3(MTOT / 128, N1 / 128), dim3(256), 0, stream,
                     xb, wqkv_t, qb, kb, vt, nullptr, N1, DIM);

  hipLaunchKernelGGL(attn_causal, dim3(SEQ / 64, BATCH * NHEADS), dim3(256), 0, stream,
                     qb, kb, vt, ao);

  hipLaunchKernelGGL((gemm_bt<1>), dim3(MTOT / 128, DIM / 128), dim3(256), 0, stream,
                     ao, wout_t, nullptr, nullptr, nullptr, out, DIM, DIM);
}

// Round 3
// 585.016 us; speedup vs baseline: 1.6280x; 1.6280x over previous
//
#include <hip/hip_runtime.h>
#include <stdint.h>
#include <stddef.h>

typedef __attribute__((ext_vector_type(8))) short bf16x8;
typedef __attribute__((ext_vector_type(4))) float f32x4;
typedef __attribute__((ext_vector_type(4))) unsigned short u16x4;

#define BATCH 2
#define SEQ 4096
#define NHEADS 16
#define DHEAD 64
#define DIM 1024
#define MTOT 8192
#define N1 3072

__device__ __forceinline__ unsigned short f2bf(float f) {
  union { float f; unsigned u; } x; x.f = f;
  unsigned r = x.u + 0x7fffu + ((x.u >> 16) & 1u);
  return (unsigned short)(r >> 16);
}

__device__ __forceinline__ void gload_lds16(const void* g, void* l) {
  __builtin_amdgcn_global_load_lds(
      (const __attribute__((address_space(1))) void*)g,
      (__attribute__((address_space(3))) void*)l, 16, 0, 0);
}

// ---------------- f32 -> bf16 elementwise ----------------
__global__ __launch_bounds__(256) void cvt_f2b(const float* __restrict__ in,
                                               unsigned short* __restrict__ out,
                                               int n4) {
  int i = blockIdx.x * 256 + threadIdx.x;
  if (i < n4) {
    f32x4 v = ((const f32x4*)in)[i];
    u16x4 o;
#pragma unroll
    for (int j = 0; j < 4; j++) o[j] = f2bf(v[j]);
    ((u16x4*)out)[i] = o;
  }
}

// ---------------- transpose+convert: f32 (R x C) -> bf16 (C x R) ----------
__global__ void transpose_cvt(const float* __restrict__ in,
                              unsigned short* __restrict__ out, int R, int C) {
  __shared__ unsigned short t[32][33];
  int tx = threadIdx.x, ty = threadIdx.y;
  int c0 = blockIdx.x * 32, r0 = blockIdx.y * 32;
#pragma unroll
  for (int i = 0; i < 4; i++)
    t[ty + i * 8][tx] = f2bf(in[(size_t)(r0 + ty + i * 8) * C + c0 + tx]);
  __syncthreads();
#pragma unroll
  for (int i = 0; i < 4; i++)
    out[(size_t)(c0 + ty + i * 8) * R + r0 + tx] = t[tx][ty + i * 8];
}

// ---------------- GEMM: C[M,N] = A[M,K] * Bt[N,K]^T, bf16 in ----
template <int MODE>
__global__ __launch_bounds__(256) void gemm_bt(
    const unsigned short* __restrict__ A,
    const unsigned short* __restrict__ Bt,
    unsigned short* __restrict__ O0,
    unsigned short* __restrict__ O1,
    unsigned short* __restrict__ O2,
    float* __restrict__ Of,
    int N, int K) {
  __shared__ unsigned short Asl[128][32];
  __shared__ unsigned short Bsl[128][32];
  const int tid = threadIdx.x;
  const int lane = tid & 63, wv = tid >> 6;
  const int wr = wv >> 1, wc = wv & 1;
  const int m0 = blockIdx.x * 128, n0 = blockIdx.y * 128;
  const int lrow = lane >> 2, lcol = (lane & 3) * 8;
  const int fr = lane & 15, kc8 = (lane >> 4) * 8;
  f32x4 acc[4][4] = {};
  for (int k0 = 0; k0 < K; k0 += 32) {
#pragma unroll
    for (int c = 0; c < 2; c++) {
      int r = wv * 32 + c * 16 + lrow;
      gload_lds16(&A[(size_t)(m0 + r) * K + k0 + lcol], &Asl[wv * 32 + c * 16][0]);
      gload_lds16(&Bt[(size_t)(n0 + r) * K + k0 + lcol], &Bsl[wv * 32 + c * 16][0]);
    }
    __syncthreads();
    bf16x8 af[4], bfr[4];
#pragma unroll
    for (int i = 0; i < 4; i++)
      af[i] = *(const bf16x8*)&Asl[wr * 64 + i * 16 + fr][kc8];
#pragma unroll
    for (int j = 0; j < 4; j++)
      bfr[j] = *(const bf16x8*)&Bsl[wc * 64 + j * 16 + fr][kc8];
#pragma unroll
    for (int i = 0; i < 4; i++)
#pragma unroll
      for (int j = 0; j < 4; j++)
        acc[i][j] = __builtin_amdgcn_mfma_f32_16x16x32_bf16(af[i], bfr[j], acc[i][j], 0, 0, 0);
    __syncthreads();
  }
  const int rq = (lane >> 4) * 4;
#pragma unroll
  for (int i = 0; i < 4; i++) {
#pragma unroll
    for (int j = 0; j < 4; j++) {
#pragma unroll
      for (int r = 0; r < 4; r++) {
        int row = m0 + wr * 64 + i * 16 + rq + r;
        int col = n0 + wc * 64 + j * 16 + fr;
        float v = acc[i][j][r];
        if (MODE == 0) {
          int w = col >> 10, rem = col & 1023;
          int h = rem >> 6, d = rem & 63;
          int b = row >> 12, n = row & 4095;
          size_t bh = (size_t)b * NHEADS + h;
          if (w == 0)      O0[(bh * SEQ + n) * DHEAD + d] = f2bf(v * 0.125f);
          else if (w == 1) O1[(bh * SEQ + n) * DHEAD + d] = f2bf(v);
          else             O2[(bh * DHEAD + d) * SEQ + n] = f2bf(v);
        } else {
          Of[(size_t)row * N + col] = v;
        }
      }
    }
  }
}

// ---------------- causal flash attention (barrier-free, balanced) --------
// Q: [BH][SEQ][64] (pre-scaled), K: [BH][SEQ][64], Vt: [BH][64][SEQ]
// AO: [BATCH*SEQ][DIM] row-major bf16
// Each block: 4 independent waves; block handles q-tiles {pi, 63-pi} of one bh.
__device__ __forceinline__ void attn_tile(
    int qt, const unsigned short* __restrict__ Qp,
    const unsigned short* __restrict__ Kp,
    const unsigned short* __restrict__ Vp,
    unsigned short* __restrict__ AOp,   // + (b*SEQ)*DIM + h*DHEAD
    unsigned short* __restrict__ Plw,   // per-wave 16x64 region
    int lane, int wv) {
  const int fr = lane & 15, g = lane >> 4;
  const int kc8 = g * 8, rq = g * 4;
  const int q0 = qt * 64;
  const int sw = fr & 7;                 // row-XOR for swizzled P reads

  bf16x8 qf0 = *(const bf16x8*)&Qp[(size_t)(q0 + wv * 16 + fr) * DHEAD + kc8];
  bf16x8 qf1 = *(const bf16x8*)&Qp[(size_t)(q0 + wv * 16 + fr) * DHEAD + 32 + kc8];

  f32x4 oacc[4] = {};
  float mrow[4], lrow[4];
#pragma unroll
  for (int r = 0; r < 4; r++) { mrow[r] = -1e30f; lrow[r] = 0.f; }

  for (int kt = 0; kt <= qt; kt++) {
    const int k0 = kt * 64;
    // ---- prefetch V fragments (consumed at end of iteration) ----
    bf16x8 vf[4][2];
#pragma unroll
    for (int db = 0; db < 4; db++) {
      vf[db][0] = *(const bf16x8*)&Vp[(size_t)(db * 16 + fr) * SEQ + k0 + kc8];
      vf[db][1] = *(const bf16x8*)&Vp[(size_t)(db * 16 + fr) * SEQ + k0 + 32 + kc8];
    }
    // ---- S = Q K^T (pre-scaled Q) ----
    f32x4 s[4];
#pragma unroll
    for (int cb = 0; cb < 4; cb++) {
      bf16x8 kf0 = *(const bf16x8*)&Kp[(size_t)(k0 + cb * 16 + fr) * DHEAD + kc8];
      bf16x8 kf1 = *(const bf16x8*)&Kp[(size_t)(k0 + cb * 16 + fr) * DHEAD + 32 + kc8];
      f32x4 z = {};
      z = __builtin_amdgcn_mfma_f32_16x16x32_bf16(qf0, kf0, z, 0, 0, 0);
      s[cb] = __builtin_amdgcn_mfma_f32_16x16x32_bf16(qf1, kf1, z, 0, 0, 0);
    }
    // ---- causal mask on diagonal block ----
    if (kt == qt) {
#pragma unroll
      for (int cb = 0; cb < 4; cb++) {
        int kj = cb * 16 + fr;
#pragma unroll
        for (int r = 0; r < 4; r++) {
          int qi = wv * 16 + rq + r;
          if (kj > qi) s[cb][r] = -1e30f;
        }
      }
    }
    // ---- online softmax (reduce over 16 fr-lanes) ----
#pragma unroll
    for (int r = 0; r < 4; r++) {
      float t = fmaxf(fmaxf(s[0][r], s[1][r]), fmaxf(s[2][r], s[3][r]));
#pragma unroll
      for (int off = 1; off < 16; off <<= 1) t = fmaxf(t, __shfl_xor(t, off, 64));
      float mnew = fmaxf(mrow[r], t);
      float alpha = __expf(mrow[r] - mnew);
#pragma unroll
      for (int db = 0; db < 4; db++) oacc[db][r] *= alpha;
      float sum = 0.f;
#pragma unroll
      for (int cb = 0; cb < 4; cb++) {
        float pv = __expf(s[cb][r] - mnew);
        s[cb][r] = pv;
        sum += pv;
      }
#pragma unroll
      for (int off = 1; off < 16; off <<= 1) sum += __shfl_xor(sum, off, 64);
      lrow[r] = lrow[r] * alpha + sum;
      mrow[r] = mnew;
    }
    // ---- P -> per-wave LDS (XOR-swizzled 16B chunks), no barrier ----
#pragma unroll
    for (int cb = 0; cb < 4; cb++)
#pragma unroll
      for (int r = 0; r < 4; r++) {
        int row = rq + r, col = cb * 16 + fr;
        int idx = row * 64 + ((((col >> 3) ^ (row & 7)) << 3) | (col & 7));
        Plw[idx] = f2bf(s[cb][r]);
      }
    bf16x8 pa0 = *(const bf16x8*)&Plw[fr * 64 + ((g ^ sw) << 3)];
    bf16x8 pa1 = *(const bf16x8*)&Plw[fr * 64 + (((g + 4) ^ sw) << 3)];
    // ---- O += P V ----
#pragma unroll
    for (int db = 0; db < 4; db++) {
      oacc[db] = __builtin_amdgcn_mfma_f32_16x16x32_bf16(pa0, vf[db][0], oacc[db], 0, 0, 0);
      oacc[db] = __builtin_amdgcn_mfma_f32_16x16x32_bf16(pa1, vf[db][1], oacc[db], 0, 0, 0);
    }
  }

  // ---- finalize: O / l ----
#pragma unroll
  for (int r = 0; r < 4; r++) {
    float inv = __builtin_amdgcn_rcpf(lrow[r]);
#pragma unroll
    for (int db = 0; db < 4; db++) {
      int n = q0 + wv * 16 + rq + r;
      int d = db * 16 + fr;
      AOp[(size_t)n * DIM + d] = f2bf(oacc[db][r] * inv);
    }
  }
}

__global__ __launch_bounds__(256, 4) void attn_causal(
    const unsigned short* __restrict__ Q,
    const unsigned short* __restrict__ Kb,
    const unsigned short* __restrict__ Vt,
    unsigned short* __restrict__ AO) {
  // block id remap: xcd-grouped bh so each XCD's 4 bh K/V (4MB) fits its L2
  const int id = blockIdx.x;
  const int xcd = id & 7, t = id >> 3;
  const int pi = t & 31, bq = t >> 5;
  const int bh = xcd * 4 + bq;           // 0..31
  const int tid = threadIdx.x, lane = tid & 63, wv = tid >> 6;

  const unsigned short* Qp = Q + (size_t)bh * SEQ * DHEAD;
  const unsigned short* Kp = Kb + (size_t)bh * SEQ * DHEAD;
  const unsigned short* Vp = Vt + (size_t)bh * DHEAD * SEQ;
  const int b = bh >> 4, h = bh & 15;
  unsigned short* AOp = AO + (size_t)b * SEQ * DIM + h * DHEAD;

  __shared__ unsigned short Pl[4][16 * 64];
  unsigned short* Plw = &Pl[wv][0];

  attn_tile(pi, Qp, Kp, Vp, AOp, Plw, lane, wv);
  attn_tile(63 - pi, Qp, Kp, Vp, AOp, Plw, lane, wv);
}

extern "C" void kernel_launch(void* const* d_in, const int* in_sizes, int n_in,
                              void* d_out, int out_size, void* d_ws, size_t ws_size,
                              hipStream_t stream) {
  const float* x    = (const float*)d_in[0]; // [8192][1024] f32
  const float* wqkv = (const float*)d_in[1]; // [1024][3072] f32
  const float* wout = (const float*)d_in[2]; // [1024][1024] f32
  float* out = (float*)d_out;                // [8192][1024] f32

  unsigned short* ws = (unsigned short*)d_ws;
  unsigned short* xb = ws;                                   // [8192][1024]
  unsigned short* ao = ws;                                   // aliases xb
  unsigned short* wqkv_t = ws + (size_t)MTOT * DIM;          // [3072][1024]
  unsigned short* wout_t = wqkv_t + (size_t)N1 * DIM;        // [1024][1024]
  unsigned short* qb = wout_t + (size_t)DIM * DIM;           // [32][4096][64]
  unsigned short* kb = qb + (size_t)BATCH * NHEADS * SEQ * DHEAD;
  unsigned short* vt = kb + (size_t)BATCH * NHEADS * SEQ * DHEAD; // [32][64][4096]

  int n4 = (MTOT * DIM) / 4;
  hipLaunchKernelGGL(cvt_f2b, dim3(n4 / 256), dim3(256), 0, stream, x, xb, n4);

  dim3 tb(32, 8);
  hipLaunchKernelGGL(transpose_cvt, dim3(N1 / 32, DIM / 32), tb, 0, stream,
                     wqkv, wqkv_t, DIM, N1);
  hipLaunchKernelGGL(transpose_cvt, dim3(DIM / 32, DIM / 32), tb, 0, stream,
                     wout, wout_t, DIM, DIM);

  hipLaunchKernelGGL((gemm_bt<0>), dim3(MTOT / 128, N1 / 128), dim3(256), 0, stream,
                     xb, wqkv_t, qb, kb, vt, nullptr, N1, DIM);

  hipLaunchKernelGGL(attn_causal, dim3(32 * 32), dim3(256), 0, stream,
                     qb, kb, vt, ao);

  hipLaunchKernelGGL((gemm_bt<1>), dim3(MTOT / 128, DIM / 128), dim3(256), 0, stream,
                     ao, wout_t, nullptr, nullptr, nullptr, out, DIM, DIM);
}

// Round 4
// 334.946 us; speedup vs baseline: 2.8435x; 1.7466x over previous
//
#include <hip/hip_runtime.h>
#include <stdint.h>
#include <stddef.h>

typedef __attribute__((ext_vector_type(8))) short bf16x8;
typedef __attribute__((ext_vector_type(4))) float f32x4;
typedef __attribute__((ext_vector_type(4))) unsigned short u16x4;

#define BATCH 2
#define SEQ 4096
#define NHEADS 16
#define DHEAD 64
#define DIM 1024
#define MTOT 8192
#define N1 3072

__device__ __forceinline__ unsigned short f2bf(float f) {
  union { float f; unsigned u; } x; x.f = f;
  unsigned r = x.u + 0x7fffu + ((x.u >> 16) & 1u);
  return (unsigned short)(r >> 16);
}

__device__ __forceinline__ void gload_lds16(const void* g, void* l) {
  __builtin_amdgcn_global_load_lds(
      (const __attribute__((address_space(1))) void*)g,
      (__attribute__((address_space(3))) void*)l, 16, 0, 0);
}

// ---------------- f32 -> bf16 elementwise ----------------
__global__ __launch_bounds__(256) void cvt_f2b(const float* __restrict__ in,
                                               unsigned short* __restrict__ out,
                                               int n4) {
  int i = blockIdx.x * 256 + threadIdx.x;
  if (i < n4) {
    f32x4 v = ((const f32x4*)in)[i];
    u16x4 o;
#pragma unroll
    for (int j = 0; j < 4; j++) o[j] = f2bf(v[j]);
    ((u16x4*)out)[i] = o;
  }
}

// ---------------- transpose+convert: f32 (R x C) -> bf16 (C x R) ----------
__global__ void transpose_cvt(const float* __restrict__ in,
                              unsigned short* __restrict__ out, int R, int C) {
  __shared__ unsigned short t[32][33];
  int tx = threadIdx.x, ty = threadIdx.y;
  int c0 = blockIdx.x * 32, r0 = blockIdx.y * 32;
#pragma unroll
  for (int i = 0; i < 4; i++)
    t[ty + i * 8][tx] = f2bf(in[(size_t)(r0 + ty + i * 8) * C + c0 + tx]);
  __syncthreads();
#pragma unroll
  for (int i = 0; i < 4; i++)
    out[(size_t)(c0 + ty + i * 8) * R + r0 + tx] = t[tx][ty + i * 8];
}

// ---------------- GEMM: C[M,N] = A[M,K] * Bt[N,K]^T, bf16 in ----
template <int MODE>
__global__ __launch_bounds__(256) void gemm_bt(
    const unsigned short* __restrict__ A,
    const unsigned short* __restrict__ Bt,
    unsigned short* __restrict__ O0,
    unsigned short* __restrict__ O1,
    unsigned short* __restrict__ O2,
    float* __restrict__ Of,
    int N, int K) {
  __shared__ unsigned short Asl[128][32];
  __shared__ unsigned short Bsl[128][32];
  const int tid = threadIdx.x;
  const int lane = tid & 63, wv = tid >> 6;
  const int wr = wv >> 1, wc = wv & 1;
  const int m0 = blockIdx.x * 128, n0 = blockIdx.y * 128;
  const int lrow = lane >> 2, lcol = (lane & 3) * 8;
  const int fr = lane & 15, kc8 = (lane >> 4) * 8;
  f32x4 acc[4][4] = {};
  for (int k0 = 0; k0 < K; k0 += 32) {
#pragma unroll
    for (int c = 0; c < 2; c++) {
      int r = wv * 32 + c * 16 + lrow;
      gload_lds16(&A[(size_t)(m0 + r) * K + k0 + lcol], &Asl[wv * 32 + c * 16][0]);
      gload_lds16(&Bt[(size_t)(n0 + r) * K + k0 + lcol], &Bsl[wv * 32 + c * 16][0]);
    }
    __syncthreads();
    bf16x8 af[4], bfr[4];
#pragma unroll
    for (int i = 0; i < 4; i++)
      af[i] = *(const bf16x8*)&Asl[wr * 64 + i * 16 + fr][kc8];
#pragma unroll
    for (int j = 0; j < 4; j++)
      bfr[j] = *(const bf16x8*)&Bsl[wc * 64 + j * 16 + fr][kc8];
#pragma unroll
    for (int i = 0; i < 4; i++)
#pragma unroll
      for (int j = 0; j < 4; j++)
        acc[i][j] = __builtin_amdgcn_mfma_f32_16x16x32_bf16(af[i], bfr[j], acc[i][j], 0, 0, 0);
    __syncthreads();
  }
  const int rq = (lane >> 4) * 4;
#pragma unroll
  for (int i = 0; i < 4; i++) {
#pragma unroll
    for (int j = 0; j < 4; j++) {
#pragma unroll
      for (int r = 0; r < 4; r++) {
        int row = m0 + wr * 64 + i * 16 + rq + r;
        int col = n0 + wc * 64 + j * 16 + fr;
        float v = acc[i][j][r];
        if (MODE == 0) {
          int w = col >> 10, rem = col & 1023;
          int h = rem >> 6, d = rem & 63;
          int b = row >> 12, n = row & 4095;
          size_t bh = (size_t)b * NHEADS + h;
          if (w == 0)      O0[(bh * SEQ + n) * DHEAD + d] = f2bf(v * 0.125f);
          else if (w == 1) O1[(bh * SEQ + n) * DHEAD + d] = f2bf(v);
          else             O2[(bh * DHEAD + d) * SEQ + n] = f2bf(v);
        } else {
          Of[(size_t)row * N + col] = v;
        }
      }
    }
  }
}

// ---------------- causal flash attention, LDS-staged K/V -----------------
// Q: [BH][SEQ][64] (pre-scaled), K: [BH][SEQ][64], Vt: [BH][64][SEQ]
// K/V tiles staged once per block via global_load_lds (pre-swizzled source),
// double-buffered; all 4 waves share them. P per-wave in swizzled LDS.
__device__ __forceinline__ void attn_tile2(
    int qt, const unsigned short* __restrict__ Qp,
    const unsigned short* __restrict__ Kp,
    const unsigned short* __restrict__ Vp,
    unsigned short* __restrict__ AOp,
    unsigned short* __restrict__ Kl,    // [2][4096]
    unsigned short* __restrict__ Vl,    // [2][4096]
    unsigned short* __restrict__ Plw,   // per-wave 16x64
    int lane, int wv) {
  const int fr = lane & 15, g = lane >> 4;
  const int kc8 = g * 8, rq = g * 4;
  const int sw = fr & 7;
  const int q0 = qt * 64;
  // staging geometry: this lane's row/chunk for each of its 2 segments
  const int srl = lane >> 3;          // row within 8-row segment
  const int jl = lane & 7;            // lds chunk slot within row

  bf16x8 qf0 = *(const bf16x8*)&Qp[(size_t)(q0 + wv * 16 + fr) * DHEAD + kc8];
  bf16x8 qf1 = *(const bf16x8*)&Qp[(size_t)(q0 + wv * 16 + fr) * DHEAD + 32 + kc8];

  f32x4 oacc[4] = {};
  float mrow[4], lrow[4];
#pragma unroll
  for (int r = 0; r < 4; r++) { mrow[r] = -1e30f; lrow[r] = 0.f; }

  // ---- prologue: stage tile 0 into buffer 0 ----
#pragma unroll
  for (int c = 0; c < 2; c++) {
    int seg = wv * 2 + c;
    int r = seg * 8 + srl;
    int j = jl ^ (r & 7);
    gload_lds16(&Kp[(size_t)r * DHEAD + j * 8], Kl + seg * 512);
    gload_lds16(&Vp[(size_t)r * SEQ + j * 8], Vl + seg * 512);
  }
  __syncthreads();

  int cur = 0;
  for (int kt = 0; kt <= qt; kt++) {
    const int ktn = (kt < qt) ? kt + 1 : qt;
    unsigned short* Kc = Kl + cur * 4096;
    unsigned short* Vc = Vl + cur * 4096;
    unsigned short* Kn = Kl + (cur ^ 1) * 4096;
    unsigned short* Vn = Vl + (cur ^ 1) * 4096;
    // ---- issue prefetch of next tile ----
#pragma unroll
    for (int c = 0; c < 2; c++) {
      int seg = wv * 2 + c;
      int r = seg * 8 + srl;
      int j = jl ^ (r & 7);
      gload_lds16(&Kp[(size_t)(ktn * 64 + r) * DHEAD + j * 8], Kn + seg * 512);
      gload_lds16(&Vp[(size_t)r * SEQ + ktn * 64 + j * 8], Vn + seg * 512);
    }
    // ---- S = Q K^T from LDS ----
    f32x4 s[4];
    __builtin_amdgcn_s_setprio(1);
#pragma unroll
    for (int cb = 0; cb < 4; cb++) {
      bf16x8 kf0 = *(const bf16x8*)&Kc[(cb * 16 + fr) * 64 + ((g ^ sw) << 3)];
      bf16x8 kf1 = *(const bf16x8*)&Kc[(cb * 16 + fr) * 64 + (((4 + g) ^ sw) << 3)];
      f32x4 z = {};
      z = __builtin_amdgcn_mfma_f32_16x16x32_bf16(qf0, kf0, z, 0, 0, 0);
      s[cb] = __builtin_amdgcn_mfma_f32_16x16x32_bf16(qf1, kf1, z, 0, 0, 0);
    }
    __builtin_amdgcn_s_setprio(0);
    // ---- causal mask on diagonal block ----
    if (kt == qt) {
#pragma unroll
      for (int cb = 0; cb < 4; cb++) {
        int kj = cb * 16 + fr;
#pragma unroll
        for (int r = 0; r < 4; r++) {
          int qi = wv * 16 + rq + r;
          if (kj > qi) s[cb][r] = -1e30f;
        }
      }
    }
    // ---- online softmax (16-lane groups) ----
#pragma unroll
    for (int r = 0; r < 4; r++) {
      float t = fmaxf(fmaxf(s[0][r], s[1][r]), fmaxf(s[2][r], s[3][r]));
#pragma unroll
      for (int off = 1; off < 16; off <<= 1) t = fmaxf(t, __shfl_xor(t, off, 64));
      float mnew = fmaxf(mrow[r], t);
      float alpha = __expf(mrow[r] - mnew);
#pragma unroll
      for (int db = 0; db < 4; db++) oacc[db][r] *= alpha;
      float sum = 0.f;
#pragma unroll
      for (int cb = 0; cb < 4; cb++) {
        float pv = __expf(s[cb][r] - mnew);
        s[cb][r] = pv;
        sum += pv;
      }
#pragma unroll
      for (int off = 1; off < 16; off <<= 1) sum += __shfl_xor(sum, off, 64);
      lrow[r] = lrow[r] * alpha + sum;
      mrow[r] = mnew;
    }
    // ---- P -> per-wave LDS (swizzled), no cross-wave barrier needed ----
#pragma unroll
    for (int cb = 0; cb < 4; cb++)
#pragma unroll
      for (int r = 0; r < 4; r++) {
        int row = rq + r, col = cb * 16 + fr;
        int idx = row * 64 + ((((col >> 3) ^ (row & 7)) << 3) | (col & 7));
        Plw[idx] = f2bf(s[cb][r]);
      }
    bf16x8 pa0 = *(const bf16x8*)&Plw[fr * 64 + ((g ^ sw) << 3)];
    bf16x8 pa1 = *(const bf16x8*)&Plw[fr * 64 + (((4 + g) ^ sw) << 3)];
    // ---- O += P V from LDS ----
    __builtin_amdgcn_s_setprio(1);
#pragma unroll
    for (int db = 0; db < 4; db++) {
      bf16x8 vf0 = *(const bf16x8*)&Vc[(db * 16 + fr) * 64 + ((g ^ sw) << 3)];
      bf16x8 vf1 = *(const bf16x8*)&Vc[(db * 16 + fr) * 64 + (((4 + g) ^ sw) << 3)];
      oacc[db] = __builtin_amdgcn_mfma_f32_16x16x32_bf16(pa0, vf0, oacc[db], 0, 0, 0);
      oacc[db] = __builtin_amdgcn_mfma_f32_16x16x32_bf16(pa1, vf1, oacc[db], 0, 0, 0);
    }
    __builtin_amdgcn_s_setprio(0);
    // ---- drain prefetch, flip buffers ----
    __syncthreads();
    cur ^= 1;
  }

  // ---- finalize: O / l ----
#pragma unroll
  for (int r = 0; r < 4; r++) {
    float inv = __builtin_amdgcn_rcpf(lrow[r]);
#pragma unroll
    for (int db = 0; db < 4; db++) {
      int n = q0 + wv * 16 + rq + r;
      int d = db * 16 + fr;
      AOp[(size_t)n * DIM + d] = f2bf(oacc[db][r] * inv);
    }
  }
}

__global__ __launch_bounds__(256, 4) void attn_causal(
    const unsigned short* __restrict__ Q,
    const unsigned short* __restrict__ Kb,
    const unsigned short* __restrict__ Vt,
    unsigned short* __restrict__ AO) {
  const int id = blockIdx.x;
  const int xcd = id & 7, t = id >> 3;
  const int pi = t & 31, bq = t >> 5;
  const int bh = xcd * 4 + bq;           // 0..31
  const int tid = threadIdx.x, lane = tid & 63, wv = tid >> 6;

  const unsigned short* Qp = Q + (size_t)bh * SEQ * DHEAD;
  const unsigned short* Kp = Kb + (size_t)bh * SEQ * DHEAD;
  const unsigned short* Vp = Vt + (size_t)bh * DHEAD * SEQ;
  const int b = bh >> 4, h = bh & 15;
  unsigned short* AOp = AO + (size_t)b * SEQ * DIM + h * DHEAD;

  __shared__ unsigned short Kl[2][4096];
  __shared__ unsigned short Vl[2][4096];
  __shared__ unsigned short Pl[4][1024];
  unsigned short* Plw = &Pl[wv][0];

  attn_tile2(pi, Qp, Kp, Vp, AOp, &Kl[0][0], &Vl[0][0], Plw, lane, wv);
  attn_tile2(63 - pi, Qp, Kp, Vp, AOp, &Kl[0][0], &Vl[0][0], Plw, lane, wv);
}

extern "C" void kernel_launch(void* const* d_in, const int* in_sizes, int n_in,
                              void* d_out, int out_size, void* d_ws, size_t ws_size,
                              hipStream_t stream) {
  const float* x    = (const float*)d_in[0]; // [8192][1024] f32
  const float* wqkv = (const float*)d_in[1]; // [1024][3072] f32
  const float* wout = (const float*)d_in[2]; // [1024][1024] f32
  float* out = (float*)d_out;                // [8192][1024] f32

  unsigned short* ws = (unsigned short*)d_ws;
  unsigned short* xb = ws;                                   // [8192][1024]
  unsigned short* ao = ws;                                   // aliases xb
  unsigned short* wqkv_t = ws + (size_t)MTOT * DIM;          // [3072][1024]
  unsigned short* wout_t = wqkv_t + (size_t)N1 * DIM;        // [1024][1024]
  unsigned short* qb = wout_t + (size_t)DIM * DIM;           // [32][4096][64]
  unsigned short* kb = qb + (size_t)BATCH * NHEADS * SEQ * DHEAD;
  unsigned short* vt = kb + (size_t)BATCH * NHEADS * SEQ * DHEAD; // [32][64][4096]

  int n4 = (MTOT * DIM) / 4;
  hipLaunchKernelGGL(cvt_f2b, dim3(n4 / 256), dim3(256), 0, stream, x, xb, n4);

  dim3 tb(32, 8);
  hipLaunchKernelGGL(transpose_cvt, dim3(N1 / 32, DIM / 32), tb, 0, stream,
                     wqkv, wqkv_t, DIM, N1);
  hipLaunchKernelGGL(transpose_cvt, dim3(DIM / 32, DIM / 32), tb, 0, stream,
                     wout, wout_t, DIM, DIM);

  hipLaunchKernelGGL((gemm_bt<0>), dim3(MTOT / 128, N1 / 128), dim3(256), 0, stream,
                     xb, wqkv_t, qb, kb, vt, nullptr, N1, DIM);

  hipLaunchKernelGGL(attn_causal, dim3(32 * 32), dim3(256), 0, stream,
                     qb, kb, vt, ao);

  hipLaunchKernelGGL((gemm_bt<1>), dim3(MTOT / 128, DIM / 128), dim3(256), 0, stream,
                     ao, wout_t, nullptr, nullptr, nullptr, out, DIM, DIM);
}

// Round 6
// 263.077 us; speedup vs baseline: 3.6203x; 1.2732x over previous
//
#include <hip/hip_runtime.h>
#include <stdint.h>
#include <stddef.h>

typedef __attribute__((ext_vector_type(8))) short bf16x8;
typedef __attribute__((ext_vector_type(4))) float f32x4;
typedef __attribute__((ext_vector_type(4))) unsigned short u16x4;
typedef __attribute__((ext_vector_type(4))) unsigned int u32x4;

#define BATCH 2
#define SEQ 4096
#define NHEADS 16
#define DHEAD 64
#define DIM 1024
#define MTOT 8192
#define N1 3072

__device__ __forceinline__ unsigned short f2bf(float f) {
  union { float f; unsigned u; } x; x.f = f;
  unsigned r = x.u + 0x7fffu + ((x.u >> 16) & 1u);
  return (unsigned short)(r >> 16);
}

__device__ __forceinline__ unsigned pk_bf16(float a, float b) {
  unsigned d;
  asm("v_cvt_pk_bf16_f32 %0, %1, %2" : "=v"(d) : "v"(a), "v"(b));
  return d;
}

__device__ __forceinline__ void gload_lds16(const void* g, void* l) {
  __builtin_amdgcn_global_load_lds(
      (const __attribute__((address_space(1))) void*)g,
      (__attribute__((address_space(3))) void*)l, 16, 0, 0);
}

// ---------------- f32 -> bf16 elementwise ----------------
__global__ __launch_bounds__(256) void cvt_f2b(const float* __restrict__ in,
                                               unsigned short* __restrict__ out,
                                               int n4) {
  int i = blockIdx.x * 256 + threadIdx.x;
  if (i < n4) {
    f32x4 v = ((const f32x4*)in)[i];
    u16x4 o;
#pragma unroll
    for (int j = 0; j < 4; j++) o[j] = f2bf(v[j]);
    ((u16x4*)out)[i] = o;
  }
}

// ---------------- transpose+convert: f32 (R x C) -> bf16 (C x R) ----------
__global__ void transpose_cvt(const float* __restrict__ in,
                              unsigned short* __restrict__ out, int R, int C) {
  __shared__ unsigned short t[32][33];
  int tx = threadIdx.x, ty = threadIdx.y;
  int c0 = blockIdx.x * 32, r0 = blockIdx.y * 32;
#pragma unroll
  for (int i = 0; i < 4; i++)
    t[ty + i * 8][tx] = f2bf(in[(size_t)(r0 + ty + i * 8) * C + c0 + tx]);
  __syncthreads();
#pragma unroll
  for (int i = 0; i < 4; i++)
    out[(size_t)(c0 + ty + i * 8) * R + r0 + tx] = t[tx][ty + i * 8];
}

// ---------------- GEMM: C[M,N] = A[M,K] * Bt[N,K]^T, bf16 in ----
template <int MODE>
__global__ __launch_bounds__(256) void gemm_bt(
    const unsigned short* __restrict__ A,
    const unsigned short* __restrict__ Bt,
    unsigned short* __restrict__ O0,
    unsigned short* __restrict__ O1,
    unsigned short* __restrict__ O2,
    float* __restrict__ Of,
    int N, int K) {
  __shared__ unsigned short Asl[128][32];
  __shared__ unsigned short Bsl[128][32];
  const int tid = threadIdx.x;
  const int lane = tid & 63, wv = tid >> 6;
  const int wr = wv >> 1, wc = wv & 1;
  const int m0 = blockIdx.x * 128, n0 = blockIdx.y * 128;
  const int lrow = lane >> 2, lcol = (lane & 3) * 8;
  const int fr = lane & 15, kc8 = (lane >> 4) * 8;
  f32x4 acc[4][4] = {};
  for (int k0 = 0; k0 < K; k0 += 32) {
#pragma unroll
    for (int c = 0; c < 2; c++) {
      int r = wv * 32 + c * 16 + lrow;
      gload_lds16(&A[(size_t)(m0 + r) * K + k0 + lcol], &Asl[wv * 32 + c * 16][0]);
      gload_lds16(&Bt[(size_t)(n0 + r) * K + k0 + lcol], &Bsl[wv * 32 + c * 16][0]);
    }
    __syncthreads();
    bf16x8 af[4], bfr[4];
#pragma unroll
    for (int i = 0; i < 4; i++)
      af[i] = *(const bf16x8*)&Asl[wr * 64 + i * 16 + fr][kc8];
#pragma unroll
    for (int j = 0; j < 4; j++)
      bfr[j] = *(const bf16x8*)&Bsl[wc * 64 + j * 16 + fr][kc8];
#pragma unroll
    for (int i = 0; i < 4; i++)
#pragma unroll
      for (int j = 0; j < 4; j++)
        acc[i][j] = __builtin_amdgcn_mfma_f32_16x16x32_bf16(af[i], bfr[j], acc[i][j], 0, 0, 0);
    __syncthreads();
  }
  const int rq = (lane >> 4) * 4;
#pragma unroll
  for (int i = 0; i < 4; i++) {
#pragma unroll
    for (int j = 0; j < 4; j++) {
#pragma unroll
      for (int r = 0; r < 4; r++) {
        int row = m0 + wr * 64 + i * 16 + rq + r;
        int col = n0 + wc * 64 + j * 16 + fr;
        float v = acc[i][j][r];
        if (MODE == 0) {
          int w = col >> 10, rem = col & 1023;
          int h = rem >> 6, d = rem & 63;
          int b = row >> 12, n = row & 4095;
          size_t bh = (size_t)b * NHEADS + h;
          if (w == 0)      O0[(bh * SEQ + n) * DHEAD + d] = f2bf(v * 0.125f);
          else if (w == 1) O1[(bh * SEQ + n) * DHEAD + d] = f2bf(v);
          else             O2[(bh * DHEAD + d) * SEQ + n] = f2bf(v);
        } else {
          Of[(size_t)row * N + col] = v;
        }
      }
    }
  }
}

// ---------------- causal flash attention, swapped QK^T, in-reg softmax ----
// Q: [BH][SEQ][64] (pre-scaled), K: [BH][SEQ][64], Vt: [BH][64][SEQ]
// S^T = mfma(K,Q): lane holds 16 S values of q-row (lane&15), k = cb*16+rq+r.
__device__ __forceinline__ void attn_tile3(
    int qt, const unsigned short* __restrict__ Qp,
    const unsigned short* __restrict__ Kp,
    const unsigned short* __restrict__ Vp,
    unsigned short* __restrict__ AOp,
    unsigned short* __restrict__ Kl,    // [2][4096]
    unsigned short* __restrict__ Vl,    // [2][4096]
    int lane, int wv) {
  const int fr = lane & 15, g = lane >> 4;
  const int kc8 = g * 8, rq = g * 4;
  const int sw = fr & 7;
  const int q0 = qt * 64;
  const int srl = lane >> 3;          // row within 8-row segment
  const int jl = lane & 7;            // lds chunk slot within row

  bf16x8 qf0 = *(const bf16x8*)&Qp[(size_t)(q0 + wv * 16 + fr) * DHEAD + kc8];
  bf16x8 qf1 = *(const bf16x8*)&Qp[(size_t)(q0 + wv * 16 + fr) * DHEAD + 32 + kc8];

  f32x4 oacc[4] = {};
  float mrow = -1e30f, lrow = 0.f;

  // ---- prologue: stage tile 0 into buffer 0 ----
#pragma unroll
  for (int c = 0; c < 2; c++) {
    int seg = wv * 2 + c;
    int r = seg * 8 + srl;
    int j = jl ^ (r & 7);
    gload_lds16(&Kp[(size_t)r * DHEAD + j * 8], Kl + seg * 512);
    gload_lds16(&Vp[(size_t)r * SEQ + j * 8], Vl + seg * 512);
  }
  __syncthreads();

  int cur = 0;
  for (int kt = 0; kt <= qt; kt++) {
    const int ktn = (kt < qt) ? kt + 1 : qt;
    unsigned short* Kc = Kl + cur * 4096;
    unsigned short* Vc = Vl + cur * 4096;
    unsigned short* Kn = Kl + (cur ^ 1) * 4096;
    unsigned short* Vn = Vl + (cur ^ 1) * 4096;
    // ---- issue prefetch of next tile ----
#pragma unroll
    for (int c = 0; c < 2; c++) {
      int seg = wv * 2 + c;
      int r = seg * 8 + srl;
      int j = jl ^ (r & 7);
      gload_lds16(&Kp[(size_t)(ktn * 64 + r) * DHEAD + j * 8], Kn + seg * 512);
      gload_lds16(&Vp[(size_t)r * SEQ + ktn * 64 + j * 8], Vn + seg * 512);
    }
    // ---- S^T = K Q^T from LDS (A=K rows, B=Q) ----
    f32x4 sv[4];
    __builtin_amdgcn_s_setprio(1);
#pragma unroll
    for (int cb = 0; cb < 4; cb++) {
      bf16x8 kf0 = *(const bf16x8*)&Kc[(cb * 16 + fr) * 64 + ((g ^ sw) << 3)];
      bf16x8 kf1 = *(const bf16x8*)&Kc[(cb * 16 + fr) * 64 + (((4 + g) ^ sw) << 3)];
      f32x4 z = {};
      z = __builtin_amdgcn_mfma_f32_16x16x32_bf16(kf0, qf0, z, 0, 0, 0);
      sv[cb] = __builtin_amdgcn_mfma_f32_16x16x32_bf16(kf1, qf1, z, 0, 0, 0);
    }
    __builtin_amdgcn_s_setprio(0);
    // ---- causal mask on diagonal block: k = cb*16+rq+r, q = wv*16+fr ----
    if (kt == qt) {
#pragma unroll
      for (int cb = 0; cb < 4; cb++)
#pragma unroll
        for (int r = 0; r < 4; r++)
          if (cb * 16 + rq + r > wv * 16 + fr) sv[cb][r] = -1e30f;
    }
    // ---- online softmax, lane-local row ----
    float c0 = fmaxf(fmaxf(sv[0][0], sv[0][1]), fmaxf(sv[0][2], sv[0][3]));
    float c1 = fmaxf(fmaxf(sv[1][0], sv[1][1]), fmaxf(sv[1][2], sv[1][3]));
    float c2 = fmaxf(fmaxf(sv[2][0], sv[2][1]), fmaxf(sv[2][2], sv[2][3]));
    float c3 = fmaxf(fmaxf(sv[3][0], sv[3][1]), fmaxf(sv[3][2], sv[3][3]));
    float pmax = fmaxf(fmaxf(c0, c1), fmaxf(c2, c3));
    pmax = fmaxf(pmax, __shfl_xor(pmax, 16, 64));
    pmax = fmaxf(pmax, __shfl_xor(pmax, 32, 64));
    if (__any(pmax - mrow > 8.f)) {   // rescale needed (rare after warmup)
      float mnew = fmaxf(mrow, pmax);
      float alpha = __expf(mrow - mnew);
      float a0 = __shfl(alpha, rq + 0, 64);
      float a1 = __shfl(alpha, rq + 1, 64);
      float a2 = __shfl(alpha, rq + 2, 64);
      float a3 = __shfl(alpha, rq + 3, 64);
#pragma unroll
      for (int db = 0; db < 4; db++) {
        oacc[db][0] *= a0; oacc[db][1] *= a1;
        oacc[db][2] *= a2; oacc[db][3] *= a3;
      }
      lrow *= alpha;
      mrow = mnew;
    }
    float p[4][4];
#pragma unroll
    for (int cb = 0; cb < 4; cb++)
#pragma unroll
      for (int r = 0; r < 4; r++)
        p[cb][r] = __expf(sv[cb][r] - mrow);
    float t0 = (p[0][0] + p[0][1]) + (p[0][2] + p[0][3]);
    float t1 = (p[1][0] + p[1][1]) + (p[1][2] + p[1][3]);
    float t2 = (p[2][0] + p[2][1]) + (p[2][2] + p[2][3]);
    float t3 = (p[3][0] + p[3][1]) + (p[3][2] + p[3][3]);
    float lsum = (t0 + t1) + (t2 + t3);
    lsum += __shfl_xor(lsum, 16, 64);
    lsum += __shfl_xor(lsum, 32, 64);
    lrow += lsum;
    // ---- pack P to bf16 pairs ----
    // word (cb,h) on lane (fr,g') covers P[q=fr][k = cb*16 + g'*4 + 2h +{0,1}]
    unsigned A0 = pk_bf16(p[0][0], p[0][1]), A1 = pk_bf16(p[0][2], p[0][3]);
    unsigned B0 = pk_bf16(p[1][0], p[1][1]), B1 = pk_bf16(p[1][2], p[1][3]);
    unsigned C0 = pk_bf16(p[2][0], p[2][1]), C1 = pk_bf16(p[2][2], p[2][3]);
    unsigned D0 = pk_bf16(p[3][0], p[3][1]), D1 = pk_bf16(p[3][2], p[3][3]);
    // ---- exchange: dest (fr,g) needs P[q=fr][k=g*8..g*8+7] (pa0)
    //                               and P[q=fr][k=32+g*8..+7] (pa1)
    // step 1: cross-32 swap (low half exports cb1/cb3, high half cb0/cb2)
    const bool lo2 = (g < 2);
    unsigned R0 = __shfl_xor((int)(lo2 ? B0 : A0), 32, 64);
    unsigned R1 = __shfl_xor((int)(lo2 ? B1 : A1), 32, 64);
    unsigned R2 = __shfl_xor((int)(lo2 ? D0 : C0), 32, 64);
    unsigned R3 = __shfl_xor((int)(lo2 ? D1 : C1), 32, 64);
    // step 2: own-use words (consumed by this lane's own dest)
    unsigned o00 = (g == 0) ? A0 : (g == 3) ? B0 : R0;
    unsigned o01 = (g == 0) ? A1 : (g == 3) ? B1 : R1;
    unsigned o10 = (g == 0) ? C0 : (g == 3) ? D0 : R2;
    unsigned o11 = (g == 0) ? C1 : (g == 3) ? D1 : R3;
    // partner-use words (consumed by xor-16 partner's dest)
    unsigned p00 = (g == 1) ? A0 : (g == 2) ? B0 : R0;
    unsigned p01 = (g == 1) ? A1 : (g == 2) ? B1 : R1;
    unsigned p10 = (g == 1) ? C0 : (g == 2) ? D0 : R2;
    unsigned p11 = (g == 1) ? C1 : (g == 2) ? D1 : R3;
    unsigned x00 = __shfl_xor((int)p00, 16, 64);
    unsigned x01 = __shfl_xor((int)p01, 16, 64);
    unsigned x10 = __shfl_xor((int)p10, 16, 64);
    unsigned x11 = __shfl_xor((int)p11, 16, 64);
    // step 3: assemble (own slots at (g&1)*2, partner at the other pair)
    const bool odd = (g & 1);
    u32x4 f0, f1;
    f0[0] = odd ? x00 : o00; f0[1] = odd ? x01 : o01;
    f0[2] = odd ? o00 : x00; f0[3] = odd ? o01 : x01;
    f1[0] = odd ? x10 : o10; f1[1] = odd ? x11 : o11;
    f1[2] = odd ? o10 : x10; f1[3] = odd ? o11 : x11;
    bf16x8 pa0 = *(bf16x8*)&f0;
    bf16x8 pa1 = *(bf16x8*)&f1;
    // ---- O += P V from LDS ----
    __builtin_amdgcn_s_setprio(1);
#pragma unroll
    for (int db = 0; db < 4; db++) {
      bf16x8 vf0 = *(const bf16x8*)&Vc[(db * 16 + fr) * 64 + ((g ^ sw) << 3)];
      bf16x8 vf1 = *(const bf16x8*)&Vc[(db * 16 + fr) * 64 + (((4 + g) ^ sw) << 3)];
      oacc[db] = __builtin_amdgcn_mfma_f32_16x16x32_bf16(pa0, vf0, oacc[db], 0, 0, 0);
      oacc[db] = __builtin_amdgcn_mfma_f32_16x16x32_bf16(pa1, vf1, oacc[db], 0, 0, 0);
    }
    __builtin_amdgcn_s_setprio(0);
    // ---- drain prefetch, flip buffers ----
    __syncthreads();
    cur ^= 1;
  }

  // ---- finalize: O / l (l lives on lanes fr=q, fetch for rows rq+r) ----
  float i0 = __builtin_amdgcn_rcpf(__shfl(lrow, rq + 0, 64));
  float i1 = __builtin_amdgcn_rcpf(__shfl(lrow, rq + 1, 64));
  float i2 = __builtin_amdgcn_rcpf(__shfl(lrow, rq + 2, 64));
  float i3 = __builtin_amdgcn_rcpf(__shfl(lrow, rq + 3, 64));
#pragma unroll
  for (int db = 0; db < 4; db++) {
    int nb = q0 + wv * 16 + rq;
    int d = db * 16 + fr;
    AOp[(size_t)(nb + 0) * DIM + d] = f2bf(oacc[db][0] * i0);
    AOp[(size_t)(nb + 1) * DIM + d] = f2bf(oacc[db][1] * i1);
    AOp[(size_t)(nb + 2) * DIM + d] = f2bf(oacc[db][2] * i2);
    AOp[(size_t)(nb + 3) * DIM + d] = f2bf(oacc[db][3] * i3);
  }
}

__global__ __launch_bounds__(256, 4) void attn_causal(
    const unsigned short* __restrict__ Q,
    const unsigned short* __restrict__ Kb,
    const unsigned short* __restrict__ Vt,
    unsigned short* __restrict__ AO) {
  const int id = blockIdx.x;
  const int xcd = id & 7, t = id >> 3;
  const int pi = t & 31, bq = t >> 5;
  const int bh = xcd * 4 + bq;           // 0..31
  const int tid = threadIdx.x, lane = tid & 63, wv = tid >> 6;

  const unsigned short* Qp = Q + (size_t)bh * SEQ * DHEAD;
  const unsigned short* Kp = Kb + (size_t)bh * SEQ * DHEAD;
  const unsigned short* Vp = Vt + (size_t)bh * DHEAD * SEQ;
  const int b = bh >> 4, h = bh & 15;
  unsigned short* AOp = AO + (size_t)b * SEQ * DIM + h * DHEAD;

  __shared__ unsigned short Kl[2][4096];
  __shared__ unsigned short Vl[2][4096];

  attn_tile3(pi, Qp, Kp, Vp, AOp, &Kl[0][0], &Vl[0][0], lane, wv);
  attn_tile3(63 - pi, Qp, Kp, Vp, AOp, &Kl[0][0], &Vl[0][0], lane, wv);
}

extern "C" void kernel_launch(void* const* d_in, const int* in_sizes, int n_in,
                              void* d_out, int out_size, void* d_ws, size_t ws_size,
                              hipStream_t stream) {
  const float* x    = (const float*)d_in[0]; // [8192][1024] f32
  const float* wqkv = (const float*)d_in[1]; // [1024][3072] f32
  const float* wout = (const float*)d_in[2]; // [1024][1024] f32
  float* out = (float*)d_out;                // [8192][1024] f32

  unsigned short* ws = (unsigned short*)d_ws;
  unsigned short* xb = ws;                                   // [8192][1024]
  unsigned short* ao = ws;                                   // aliases xb
  unsigned short* wqkv_t = ws + (size_t)MTOT * DIM;          // [3072][1024]
  unsigned short* wout_t = wqkv_t + (size_t)N1 * DIM;        // [1024][1024]
  unsigned short* qb = wout_t + (size_t)DIM * DIM;           // [32][4096][64]
  unsigned short* kb = qb + (size_t)BATCH * NHEADS * SEQ * DHEAD;
  unsigned short* vt = kb + (size_t)BATCH * NHEADS * SEQ * DHEAD; // [32][64][4096]

  int n4 = (MTOT * DIM) / 4;
  hipLaunchKernelGGL(cvt_f2b, dim3(n4 / 256), dim3(256), 0, stream, x, xb, n4);

  dim3 tb(32, 8);
  hipLaunchKernelGGL(transpose_cvt, dim3(N1 / 32, DIM / 32), tb, 0, stream,
                     wqkv, wqkv_t, DIM, N1);
  hipLaunchKernelGGL(transpose_cvt, dim3(DIM / 32, DIM / 32), tb, 0, stream,
                     wout, wout_t, DIM, DIM);

  hipLaunchKernelGGL((gemm_bt<0>), dim3(MTOT / 128, N1 / 128), dim3(256), 0, stream,
                     xb, wqkv_t, qb, kb, vt, nullptr, N1, DIM);

  hipLaunchKernelGGL(attn_causal, dim3(32 * 32), dim3(256), 0, stream,
                     qb, kb, vt, ao);

  hipLaunchKernelGGL((gemm_bt<1>), dim3(MTOT / 128, DIM / 128), dim3(256), 0, stream,
                     ao, wout_t, nullptr, nullptr, nullptr, out, DIM, DIM);
}